// Round 1
// baseline (49.924 us; speedup 1.0000x reference)
//
#include <hip/hip_runtime.h>
#include <float.h>

#define BATCH 32
#define NP 512
#define NG 512
#define TSTEP 10
#define NCHUNK 8
#define CHUNK_GT (NG / NCHUNK)          // 64 gt points per chunk
#define CHUNK_PTS (CHUNK_GT * TSTEP)    // 640 interp points per chunk

__device__ __forceinline__ float wave_reduce(float v) {
#pragma unroll
    for (int o = 32; o > 0; o >>= 1) v += __shfl_down(v, o);
    return v;
}

// ---------------- K0: init packed min array ----------------
__global__ __launch_bounds__(256) void k_init(unsigned long long* __restrict__ minpack) {
    int t = blockIdx.x * 256 + threadIdx.x;
    if (t < BATCH * NP) minpack[t] = 0xFFFFFFFFFFFFFFFFull;
}

// ---------------- K1: pred -> nearest interpolated gt (partial argmin per chunk) ----
// grid = BATCH * 2 * NCHUNK blocks, 256 threads. Thread = one pred point.
__global__ __launch_bounds__(256) void k_p2g_min(const float* __restrict__ gt,
                                                 const float* __restrict__ pred0,
                                                 unsigned long long* __restrict__ minpack) {
    __shared__ float2 sI[CHUNK_PTS];
    const int bid = blockIdx.x;
    const int ch = bid & (NCHUNK - 1);
    const int ph = (bid >> 3) & 1;
    const int b = bid >> 4;
    const float* gtb = gt + b * NG * 2;

    for (int k = threadIdx.x; k < CHUNK_PTS; k += 256) {
        int j = ch * CHUNK_GT + k / TSTEP;
        int tt = k - (k / TSTEP) * TSTEP;
        int jm = (j + NG - 1) & (NG - 1);   // roll by 1: predecessor
        float tf = (float)tt / 10.0f;
        float uf = 1.0f - tf;
        sI[k] = make_float2(gtb[2 * j] * tf + gtb[2 * jm] * uf,
                            gtb[2 * j + 1] * tf + gtb[2 * jm + 1] * uf);
    }
    __syncthreads();

    const int p = ph * 256 + threadIdx.x;
    const float px = pred0[(b * NP + p) * 2];
    const float py = pred0[(b * NP + p) * 2 + 1];
    float best = FLT_MAX;
    int bi = 0;
#pragma unroll 8
    for (int k = 0; k < CHUNK_PTS; ++k) {
        float2 g = sI[k];
        float dx = g.x - px, dy = g.y - py;
        float d = dx * dx + dy * dy;
        if (d < best) { best = d; bi = k; }   // strict < keeps first (lowest idx)
    }
    unsigned long long pack =
        ((unsigned long long)__float_as_uint(best) << 32) | (unsigned)(ch * CHUNK_PTS + bi);
    // dist >= 0 so fp32 bit pattern is order-monotonic; ties -> lower idx wins,
    // matching jnp.argmin first-min semantics exactly.
    atomicMin(minpack + b * NP + p, pack);
}

// ---------------- K2: gather nearest gt coords, reduce |pred1 - nearest| -----------
__global__ __launch_bounds__(256) void k_p2g_gather(const float* __restrict__ gt,
                                                    const float* __restrict__ pred1,
                                                    const unsigned long long* __restrict__ minpack,
                                                    float* __restrict__ bsums) {
    __shared__ float sw[4];
    int t = blockIdx.x * 256 + threadIdx.x;   // 0..16383 = (b,p)
    int b = t >> 9;
    unsigned idx = (unsigned)(minpack[t] & 0xFFFFFFFFull);
    int j = idx / TSTEP;
    int tt = idx - j * TSTEP;
    int jm = (j + NG - 1) & (NG - 1);
    const float* gtb = gt + b * NG * 2;
    float tf = (float)tt / 10.0f, uf = 1.0f - tf;
    float nx = gtb[2 * j] * tf + gtb[2 * jm] * uf;
    float ny = gtb[2 * j + 1] * tf + gtb[2 * jm + 1] * uf;
    float s = fabsf(pred1[2 * t] - nx) + fabsf(pred1[2 * t + 1] - ny);

    s = wave_reduce(s);
    int lane = threadIdx.x & 63, w = threadIdx.x >> 6;
    if (lane == 0) sw[w] = s;
    __syncthreads();
    if (threadIdx.x == 0) bsums[blockIdx.x] = sw[0] + sw[1] + sw[2] + sw[3];
}

// ---------------- K3: gt -> nearest pred, masked L1 ----------------
// grid = BATCH blocks, 512 threads. Thread = one gt point.
__global__ __launch_bounds__(512) void k_g2p(const float* __restrict__ gt,
                                             const float* __restrict__ pred0,
                                             const float* __restrict__ pred1,
                                             const float* __restrict__ mask,
                                             float* __restrict__ lsums,
                                             float* __restrict__ msums) {
    __shared__ float2 sP[NP];
    __shared__ float swl[8], swm[8];
    int b = blockIdx.x, g = threadIdx.x;
    sP[g] = make_float2(pred0[(b * NP + g) * 2], pred0[(b * NP + g) * 2 + 1]);
    __syncthreads();

    float gx = gt[(b * NG + g) * 2], gy = gt[(b * NG + g) * 2 + 1];
    float best = FLT_MAX;
    int bi = 0;
#pragma unroll 8
    for (int p = 0; p < NP; ++p) {
        float2 q = sP[p];
        float dx = gx - q.x, dy = gy - q.y;
        float d = dx * dx + dy * dy;
        if (d < best) { best = d; bi = p; }
    }
    float m = mask[b * NG + g];
    float l = m * (fabsf(pred1[(b * NP + bi) * 2] - gx) +
                   fabsf(pred1[(b * NP + bi) * 2 + 1] - gy));
    float mm = 2.0f * m;   // mask broadcast over 2 coords

    l = wave_reduce(l);
    mm = wave_reduce(mm);
    int lane = threadIdx.x & 63, w = threadIdx.x >> 6;
    if (lane == 0) { swl[w] = l; swm[w] = mm; }
    __syncthreads();
    if (threadIdx.x == 0) {
        float L = 0.f, M = 0.f;
#pragma unroll
        for (int i = 0; i < 8; ++i) { L += swl[i]; M += swm[i]; }
        lsums[b] = L;
        msums[b] = M;
    }
}

// ---------------- K4: final combine ----------------
__global__ __launch_bounds__(64) void k_final(const float* __restrict__ p1sums,
                                              const float* __restrict__ lsums,
                                              const float* __restrict__ msums,
                                              float* __restrict__ out) {
    int lane = threadIdx.x;
    float a = p1sums[lane];                       // 64 block sums from K2
    float l = lane < 32 ? lsums[lane] : 0.0f;     // 32 batch sums from K3
    float m = lane < 32 ? msums[lane] : 0.0f;
    a = wave_reduce(a);
    l = wave_reduce(l);
    m = wave_reduce(m);
    if (lane == 0) {
        float loss_p2g = a / 32768.0f;            // mean over B*NP*2
        out[0] = (l / (m + 1.0f) + loss_p2g) * 0.5f;
    }
}

extern "C" void kernel_launch(void* const* d_in, const int* in_sizes, int n_in,
                              void* d_out, int out_size, void* d_ws, size_t ws_size,
                              hipStream_t stream) {
    const float* ini_pred = (const float*)d_in[0];   // [B,NP,2]
    const float* pred1    = (const float*)d_in[1];   // [B,NP,2]
    const float* gt       = (const float*)d_in[2];   // [B,NG,2]
    const float* mask     = (const float*)d_in[3];   // [B,NG]
    float* out = (float*)d_out;

    unsigned long long* minpack = (unsigned long long*)d_ws;              // 16384 u64
    float* p1sums = (float*)((char*)d_ws + BATCH * NP * sizeof(unsigned long long));
    float* lsums = p1sums + 64;
    float* msums = lsums + 32;

    hipLaunchKernelGGL(k_init, dim3(64), dim3(256), 0, stream, minpack);
    hipLaunchKernelGGL(k_p2g_min, dim3(BATCH * 2 * NCHUNK), dim3(256), 0, stream,
                       gt, ini_pred, minpack);
    hipLaunchKernelGGL(k_p2g_gather, dim3(64), dim3(256), 0, stream,
                       gt, pred1, minpack, p1sums);
    hipLaunchKernelGGL(k_g2p, dim3(BATCH), dim3(512), 0, stream,
                       gt, ini_pred, pred1, mask, lsums, msums);
    hipLaunchKernelGGL(k_final, dim3(1), dim3(64), 0, stream,
                       p1sums, lsums, msums, out);
}

// Round 2
// 37.371 us; speedup vs baseline: 1.3359x; 1.3359x over previous
//
#include <hip/hip_runtime.h>
#include <float.h>

#define BATCH 32
#define NP 512
#define NG 512
#define TSTEP 10
#define NI (NG * TSTEP)                  // 5120 interpolated gt points
#define NCHUNK 16
#define CHUNK_PTS (NI / NCHUNK)          // 320 interp points per chunk
#define NB_P2G (BATCH * 2 * NCHUNK)      // 1024 blocks
#define NB_G2P (BATCH * 2)               // 64 blocks
#define NPACK (BATCH * NP)               // 16384

__device__ __forceinline__ float wave_reduce(float v) {
#pragma unroll
    for (int o = 32; o > 0; o >>= 1) v += __shfl_down(v, o);
    return v;
}

// Combine 4 (dist, local-idx) accumulators into one packed u64.
// dist >= 0 -> fp32 bit pattern order-monotonic; idx in low bits -> on equal
// dist the LOWER global index wins == jnp.argmin first-min semantics.
__device__ __forceinline__ unsigned long long pack_min4(
    float d0, int i0, float d1, int i1, float d2, int i2, float d3, int i3, int base) {
    unsigned long long p0 = ((unsigned long long)__float_as_uint(d0) << 32) | (unsigned)(base + i0);
    unsigned long long p1 = ((unsigned long long)__float_as_uint(d1) << 32) | (unsigned)(base + i1);
    unsigned long long p2 = ((unsigned long long)__float_as_uint(d2) << 32) | (unsigned)(base + i2);
    unsigned long long p3 = ((unsigned long long)__float_as_uint(d3) << 32) | (unsigned)(base + i3);
    unsigned long long a = p0 < p1 ? p0 : p1;
    unsigned long long b = p2 < p3 ? p2 : p3;
    return a < b ? a : b;
}

// ---------------- Kernel A: all argmin work in one launch ----------------
// blocks [0, NB_P2G): pred -> nearest interpolated-gt, per-chunk minima -> packs
// blocks [NB_P2G, NB_P2G+NB_G2P): gt -> nearest pred (full), masked L1 -> partials
__global__ __launch_bounds__(256) void k_argmin(
    const float* __restrict__ gt, const float* __restrict__ pred0,
    const float* __restrict__ pred1, const float* __restrict__ mask,
    unsigned long long* __restrict__ packs,
    float* __restrict__ gsum, float* __restrict__ msum,
    unsigned int* __restrict__ counter) {
    const int bid = blockIdx.x, tid = threadIdx.x;
    if (bid == 0 && tid == 0) *counter = 0u;   // re-armed every call (A completes before B)

    if (bid < NB_P2G) {
        __shared__ float2 sI[CHUNK_PTS];
        const int ch = bid & (NCHUNK - 1);
        const int ph = (bid >> 4) & 1;
        const int b  = bid >> 5;
        const float* gtb = gt + b * NG * 2;
        for (int k = tid; k < CHUNK_PTS; k += 256) {
            int kk = ch * CHUNK_PTS + k;
            int j  = kk / TSTEP;
            int tt = kk - j * TSTEP;
            int jm = (j + NG - 1) & (NG - 1);        // roll-by-1 predecessor
            float tf = (float)tt / 10.0f, uf = 1.0f - tf;
            sI[k] = make_float2(gtb[2 * j] * tf + gtb[2 * jm] * uf,
                                gtb[2 * j + 1] * tf + gtb[2 * jm + 1] * uf);
        }
        __syncthreads();

        const int p = ph * 256 + tid;
        const float px = pred0[(b * NP + p) * 2];
        const float py = pred0[(b * NP + p) * 2 + 1];
        float b0 = FLT_MAX, b1 = FLT_MAX, b2 = FLT_MAX, b3 = FLT_MAX;
        int i0 = 0, i1 = 0, i2 = 0, i3 = 0;
        const float4* s4 = (const float4*)sI;
#pragma unroll 4
        for (int i = 0; i < CHUNK_PTS / 4; ++i) {
            float4 cA = s4[2 * i], cB = s4[2 * i + 1];   // broadcast LDS reads
            float dx, dy, d;
            dx = cA.x - px; dy = cA.y - py; d = dx * dx + dy * dy; if (d < b0) { b0 = d; i0 = 4 * i;     }
            dx = cA.z - px; dy = cA.w - py; d = dx * dx + dy * dy; if (d < b1) { b1 = d; i1 = 4 * i + 1; }
            dx = cB.x - px; dy = cB.y - py; d = dx * dx + dy * dy; if (d < b2) { b2 = d; i2 = 4 * i + 2; }
            dx = cB.z - px; dy = cB.w - py; d = dx * dx + dy * dy; if (d < b3) { b3 = d; i3 = 4 * i + 3; }
        }
        packs[ch * NPACK + b * NP + p] =
            pack_min4(b0, i0, b1, i1, b2, i2, b3, i3, ch * CHUNK_PTS);
    } else {
        __shared__ float2 sP[NP];
        __shared__ float swl[4], swm[4];
        const int gb = bid - NB_P2G;
        const int b = gb >> 1, gh = gb & 1;
        for (int k = tid; k < NP; k += 256)
            sP[k] = make_float2(pred0[(b * NP + k) * 2], pred0[(b * NP + k) * 2 + 1]);
        __syncthreads();

        const int g = gh * 256 + tid;
        const float gx = gt[(b * NG + g) * 2], gy = gt[(b * NG + g) * 2 + 1];
        float b0 = FLT_MAX, b1 = FLT_MAX, b2 = FLT_MAX, b3 = FLT_MAX;
        int i0 = 0, i1 = 0, i2 = 0, i3 = 0;
        const float4* s4 = (const float4*)sP;
#pragma unroll 4
        for (int i = 0; i < NP / 4; ++i) {
            float4 cA = s4[2 * i], cB = s4[2 * i + 1];
            float dx, dy, d;
            dx = gx - cA.x; dy = gy - cA.y; d = dx * dx + dy * dy; if (d < b0) { b0 = d; i0 = 4 * i;     }
            dx = gx - cA.z; dy = gy - cA.w; d = dx * dx + dy * dy; if (d < b1) { b1 = d; i1 = 4 * i + 1; }
            dx = gx - cB.x; dy = gy - cB.y; d = dx * dx + dy * dy; if (d < b2) { b2 = d; i2 = 4 * i + 2; }
            dx = gx - cB.z; dy = gy - cB.w; d = dx * dx + dy * dy; if (d < b3) { b3 = d; i3 = 4 * i + 3; }
        }
        const int bi = (int)(pack_min4(b0, i0, b1, i1, b2, i2, b3, i3, 0) & 0xFFFFFFFFull);
        const float m = mask[b * NG + g];
        float l = m * (fabsf(pred1[(b * NP + bi) * 2] - gx) +
                       fabsf(pred1[(b * NP + bi) * 2 + 1] - gy));
        float mm = 2.0f * m;   // mask broadcast over the 2 coords
        l = wave_reduce(l);
        mm = wave_reduce(mm);
        const int lane = tid & 63, w = tid >> 6;
        if (lane == 0) { swl[w] = l; swm[w] = mm; }
        __syncthreads();
        if (tid == 0) {
            gsum[gb] = swl[0] + swl[1] + swl[2] + swl[3];
            msum[gb] = swm[0] + swm[1] + swm[2] + swm[3];
        }
    }
}

// ---------------- Kernel B: combine chunks, gather, reduce, final ----------------
__global__ __launch_bounds__(256) void k_reduce(
    const float* __restrict__ gt, const float* __restrict__ pred1,
    const unsigned long long* __restrict__ packs,
    const float* __restrict__ gsum, const float* __restrict__ msum,
    float* __restrict__ psum, unsigned int* __restrict__ counter,
    float* __restrict__ out) {
    __shared__ float sw[4];
    __shared__ int lastFlag;
    const int tid = threadIdx.x;
    const int t = blockIdx.x * 256 + tid;     // (b,p) flat
    const int b = t >> 9;

    unsigned long long best = packs[t];
#pragma unroll
    for (int ch = 1; ch < NCHUNK; ++ch) {
        unsigned long long v = packs[ch * NPACK + t];
        if (v < best) best = v;
    }
    const unsigned idx = (unsigned)(best & 0xFFFFFFFFull);
    const int j = idx / TSTEP;
    const int tt = idx - j * TSTEP;
    const int jm = (j + NG - 1) & (NG - 1);
    const float* gtb = gt + b * NG * 2;
    const float tf = (float)tt / 10.0f, uf = 1.0f - tf;
    const float nx = gtb[2 * j] * tf + gtb[2 * jm] * uf;
    const float ny = gtb[2 * j + 1] * tf + gtb[2 * jm + 1] * uf;
    float s = fabsf(pred1[2 * t] - nx) + fabsf(pred1[2 * t + 1] - ny);

    s = wave_reduce(s);
    const int lane = tid & 63, w = tid >> 6;
    if (lane == 0) sw[w] = s;
    __syncthreads();
    if (tid == 0) {
        float S = sw[0] + sw[1] + sw[2] + sw[3];
        __hip_atomic_store(&psum[blockIdx.x], S, __ATOMIC_RELAXED, __HIP_MEMORY_SCOPE_AGENT);
        unsigned tk = __hip_atomic_fetch_add(counter, 1u, __ATOMIC_ACQ_REL, __HIP_MEMORY_SCOPE_AGENT);
        lastFlag = (tk == 64 - 1);
    }
    __syncthreads();
    // Last block standing computes the final scalar (deterministic: partials fixed,
    // fixed reduce order regardless of which block is last).
    if (lastFlag && tid < 64) {
        float a = __hip_atomic_load(&psum[tid], __ATOMIC_RELAXED, __HIP_MEMORY_SCOPE_AGENT);
        float l = __hip_atomic_load(&gsum[tid], __ATOMIC_RELAXED, __HIP_MEMORY_SCOPE_AGENT);
        float m = __hip_atomic_load(&msum[tid], __ATOMIC_RELAXED, __HIP_MEMORY_SCOPE_AGENT);
        a = wave_reduce(a);
        l = wave_reduce(l);
        m = wave_reduce(m);
        if (tid == 0)
            out[0] = (l / (m + 1.0f) + a / (float)(BATCH * NP * 2)) * 0.5f;
    }
}

extern "C" void kernel_launch(void* const* d_in, const int* in_sizes, int n_in,
                              void* d_out, int out_size, void* d_ws, size_t ws_size,
                              hipStream_t stream) {
    const float* pred0 = (const float*)d_in[0];   // ini_pred_poly [B,NP,2]
    const float* pred1 = (const float*)d_in[1];   // pred_polys_   [B,NP,2]
    const float* gt    = (const float*)d_in[2];   // gt_polys      [B,NG,2]
    const float* mask  = (const float*)d_in[3];   // keyPointsMask [B,NG]
    float* out = (float*)d_out;

    unsigned long long* packs = (unsigned long long*)d_ws;            // 16*16384*8 = 2 MB
    float* psum = (float*)((char*)d_ws + (size_t)NCHUNK * NPACK * sizeof(unsigned long long));
    float* gsum = psum + 64;
    float* msum = gsum + 64;
    unsigned int* counter = (unsigned int*)(msum + 64);

    hipLaunchKernelGGL(k_argmin, dim3(NB_P2G + NB_G2P), dim3(256), 0, stream,
                       gt, pred0, pred1, mask, packs, gsum, msum, counter);
    hipLaunchKernelGGL(k_reduce, dim3(64), dim3(256), 0, stream,
                       gt, pred1, packs, gsum, msum, psum, counter, out);
}